// Round 5
// baseline (86178.394 us; speedup 1.0000x reference)
//
#include <hip/hip_runtime.h>
#include <cstdint>

#define T_STEPS 8192
#define HDIM    768
#define G3      2304   // 3*H
#define NDR     4608   // 2*3*H
#define HC      1536   // 2*H
#define GPD     96     // workgroups per direction
#define NWG     192    // 2 dirs x 96 WGs (independent cliques)
#define C_ROWS  8      // h-rows per workgroup (2 per wave)

// ---------------------------------------------------------------------------
// GEMM: C[m][n] = sum_k X[m][k] * W[n][k] + bias[n]
// X: [M,K] row-major, W: [N,K] row-major. 128x128 tile, BK=16, 256 thr, 8x8.
// ---------------------------------------------------------------------------
__global__ __launch_bounds__(256)
void gemm_xwt(const float* __restrict__ X, const float* __restrict__ W,
              const float* __restrict__ bias, float* __restrict__ C,
              int M, int N, int K) {
    __shared__ float As[16][132];
    __shared__ float Bs[16][132];
    const int tid = threadIdx.x;
    const int m0 = blockIdx.y * 128;
    const int n0 = blockIdx.x * 128;
    const int tm = tid >> 4;
    const int tn = tid & 15;

    float acc[8][8] = {};

    for (int k0 = 0; k0 < K; k0 += 16) {
        #pragma unroll
        for (int l = 0; l < 2; ++l) {
            int idx = l * 256 + tid;
            int row = idx >> 2;
            int kc  = (idx & 3) << 2;
            float4 a = *(const float4*)(X + (size_t)(m0 + row) * K + k0 + kc);
            As[kc + 0][row] = a.x; As[kc + 1][row] = a.y;
            As[kc + 2][row] = a.z; As[kc + 3][row] = a.w;
            float4 b = *(const float4*)(W + (size_t)(n0 + row) * K + k0 + kc);
            Bs[kc + 0][row] = b.x; Bs[kc + 1][row] = b.y;
            Bs[kc + 2][row] = b.z; Bs[kc + 3][row] = b.w;
        }
        __syncthreads();
        #pragma unroll
        for (int k = 0; k < 16; ++k) {
            float4 a0 = *(const float4*)&As[k][tm * 8];
            float4 a1 = *(const float4*)&As[k][tm * 8 + 4];
            float4 b0 = *(const float4*)&Bs[k][tn * 8];
            float4 b1 = *(const float4*)&Bs[k][tn * 8 + 4];
            float av[8] = {a0.x, a0.y, a0.z, a0.w, a1.x, a1.y, a1.z, a1.w};
            float bv[8] = {b0.x, b0.y, b0.z, b0.w, b1.x, b1.y, b1.z, b1.w};
            #pragma unroll
            for (int i = 0; i < 8; ++i)
                #pragma unroll
                for (int j = 0; j < 8; ++j)
                    acc[i][j] = fmaf(av[i], bv[j], acc[i][j]);
        }
        __syncthreads();
    }

    float bfrag[8];
    #pragma unroll
    for (int j = 0; j < 8; ++j) bfrag[j] = bias[n0 + tn * 8 + j];

    #pragma unroll
    for (int i = 0; i < 8; ++i) {
        float* cp = C + (size_t)(m0 + tm * 8 + i) * N + n0 + tn * 8;
        float4 o0, o1;
        o0.x = acc[i][0] + bfrag[0]; o0.y = acc[i][1] + bfrag[1];
        o0.z = acc[i][2] + bfrag[2]; o0.w = acc[i][3] + bfrag[3];
        o1.x = acc[i][4] + bfrag[4]; o1.y = acc[i][5] + bfrag[5];
        o1.z = acc[i][6] + bfrag[6]; o1.w = acc[i][7] + bfrag[7];
        *(float4*)(cp + 0) = o0;
        *(float4*)(cp + 4) = o1;
    }
}

// ---------------------------------------------------------------------------
// GRU recurrence — wave-autonomous version. 192 WGs = 2 cliques of 96;
// each wave is a self-contained engine for 2 h-rows (all 3 gates):
//   dot = wave + 4*m  ->  wave w owns rows j0+w, j0+w+4 across gates r,z,n.
// Exchange: flat array of 768 self-validating pairs (fp32 ‖ step tag) per
// (parity, dir). Every lane polls its own 12 pairs into registers (relaxed
// agent-scope 8-B atomic loads), 72 FMAs vs register weights, 6-value
// 64-lane butterfly, lanes 0/1 do gates and publish 1 pair each.
// NO LDS, NO __syncthreads in the step loop. h_prev is a register (our own
// previous publish). Parity overwrite-safety: tag t+2 can only exist after
// every wave validated (hence consumed into registers) all step-t pairs.
// ---------------------------------------------------------------------------
__device__ __forceinline__ float sigf(float x) {
    return 1.0f / (1.0f + expf(-x));
}

__global__ __launch_bounds__(256, 1)
void gru_rec(const float* __restrict__ Gi,   // [T][2][2304]
             const float* __restrict__ whh,  // [2][2304][768]
             const float* __restrict__ bhh,  // [2][2304]
             const float* __restrict__ h0,   // [2][768] (layer slice)
             unsigned long long* __restrict__ exch, // [2 par][2 dir][768] pairs
             float* __restrict__ Hout) {     // [T][2][768]
    const int tid  = threadIdx.x;
    const int lane = tid & 63;
    const int wave = tid >> 6;
    const int bid  = blockIdx.x;
    const int d    = bid / GPD;
    const int j0   = (bid % GPD) * C_ROWS;

    // Register-resident recurrent weights: dot = wave + 4*m, 6 dots/wave.
    float4 w[6][3];
    #pragma unroll
    for (int m = 0; m < 6; ++m) {
        int dot = wave + 4 * m;
        int g = dot >> 3, jl = dot & 7;
        const float* wrow = whh + (size_t)d * G3 * HDIM
                                + (size_t)(g * 768 + j0 + jl) * HDIM;
        #pragma unroll
        for (int i = 0; i < 3; ++i)
            w[m][i] = *(const float4*)(wrow + i * 256 + lane * 4);
    }

    // Publishing lanes 0,1: per-row constants and initial h.
    const int myrow = j0 + wave + (lane == 1 ? 4 : 0);  // lanes 0,1 only
    float bh_r = 0.f, bh_z = 0.f, bh_n = 0.f, hprev = 0.f;
    if (lane < 2) {
        bh_r = bhh[d * G3 +          myrow];
        bh_z = bhh[d * G3 +  768   + myrow];
        bh_n = bhh[d * G3 + 1536   + myrow];
        hprev = h0[d * 768 + myrow];
    }

    for (int t = 0; t < T_STEPS; ++t) {
        // Gi prefetch for the 2 owned rows (in flight during the poll).
        float gi_r = 0.f, gi_z = 0.f, gi_n = 0.f;
        if (lane < 2) {
            const float* gip = Gi + ((size_t)t * 2 + d) * G3;
            gi_r = gip[         myrow];
            gi_z = gip[ 768   + myrow];
            gi_n = gip[1536   + myrow];
        }

        // --- Gather h_{t-1}: 12 values per lane, straight to registers ---
        float hv[12];
        if (t == 0) {
            const float* src = h0 + d * 768;
            #pragma unroll
            for (int i = 0; i < 3; ++i)
                #pragma unroll
                for (int k = 0; k < 4; ++k)
                    hv[i * 4 + k] = src[i * 256 + lane * 4 + k];
        } else {
            const unsigned long long* src =
                exch + (size_t)((((t - 1) & 1) * 2 + d)) * HDIM;
            unsigned long long v[12];
            bool ok = false;
            do {
                #pragma unroll
                for (int i = 0; i < 3; ++i)
                    #pragma unroll
                    for (int k = 0; k < 4; ++k)
                        v[i * 4 + k] = __hip_atomic_load(
                            src + i * 256 + lane * 4 + k,
                            __ATOMIC_RELAXED, __HIP_MEMORY_SCOPE_AGENT);
                ok = true;
                #pragma unroll
                for (int n = 0; n < 12; ++n)
                    ok &= ((unsigned)v[n] >= (unsigned)t);
            } while (!ok);
            #pragma unroll
            for (int n = 0; n < 12; ++n)
                hv[n] = __uint_as_float((unsigned)(v[n] >> 32));
        }

        // --- 6 dots x 12 MACs against register weights ---
        float S[6];
        #pragma unroll
        for (int m = 0; m < 6; ++m) {
            float s = 0.f;
            s = fmaf(w[m][0].x, hv[0],  s); s = fmaf(w[m][0].y, hv[1],  s);
            s = fmaf(w[m][0].z, hv[2],  s); s = fmaf(w[m][0].w, hv[3],  s);
            s = fmaf(w[m][1].x, hv[4],  s); s = fmaf(w[m][1].y, hv[5],  s);
            s = fmaf(w[m][1].z, hv[6],  s); s = fmaf(w[m][1].w, hv[7],  s);
            s = fmaf(w[m][2].x, hv[8],  s); s = fmaf(w[m][2].y, hv[9],  s);
            s = fmaf(w[m][2].z, hv[10], s); s = fmaf(w[m][2].w, hv[11], s);
            S[m] = s;
        }

        // --- 64-lane butterfly on 6 values ---
        #pragma unroll
        for (int sft = 1; sft < 64; sft <<= 1) {
            #pragma unroll
            for (int m = 0; m < 6; ++m) S[m] += __shfl_xor(S[m], sft);
        }

        // --- Gates + publish (lanes 0,1: rows j0+wave, j0+wave+4) ---
        if (lane < 2) {
            float Sr = (lane == 0) ? S[0] : S[1];
            float Sz = (lane == 0) ? S[2] : S[3];
            float Sn = (lane == 0) ? S[4] : S[5];
            float r = sigf(gi_r + Sr + bh_r);
            float z = sigf(gi_z + Sz + bh_z);
            float n = tanhf(gi_n + r * (Sn + bh_n));
            float hn = (1.0f - z) * n + z * hprev;
            hprev = hn;
            unsigned long long pair =
                ((unsigned long long)__float_as_uint(hn) << 32)
                | (unsigned long long)(unsigned)(t + 1);
            __hip_atomic_store(
                exch + (size_t)(((t & 1) * 2 + d)) * HDIM + myrow, pair,
                __ATOMIC_RELAXED, __HIP_MEMORY_SCOPE_AGENT);
            Hout[((size_t)t * 2 + d) * 768 + myrow] = hn;
        }
    }
}

// ---------------------------------------------------------------------------
// Final FC + sigmoid: out[r] = sigmoid(fc_w[r] . hin + fc_b[r]); one wave/row.
// ---------------------------------------------------------------------------
__device__ __forceinline__ float dot4(float4 a, float4 b) {
    return a.x * b.x + a.y * b.y + a.z * b.z + a.w * b.w;
}

__global__ __launch_bounds__(64)
void fc_sig(const float* __restrict__ hin, const float* __restrict__ fw,
            const float* __restrict__ fb, float* __restrict__ out) {
    const int lane = threadIdx.x;
    const int row  = blockIdx.x;
    const float* wr = fw + (size_t)row * HC;
    float acc = 0.0f;
    #pragma unroll
    for (int i = 0; i < 6; ++i) {
        float4 w4 = *(const float4*)(wr  + i * 256 + lane * 4);
        float4 h4 = *(const float4*)(hin + i * 256 + lane * 4);
        acc += dot4(w4, h4);
    }
    #pragma unroll
    for (int s = 1; s < 64; s <<= 1) acc += __shfl_xor(acc, s);
    if (lane == 0) out[row] = sigf(acc + fb[row]);
}

// ---------------------------------------------------------------------------
extern "C" void kernel_launch(void* const* d_in, const int* in_sizes, int n_in,
                              void* d_out, int out_size, void* d_ws, size_t ws_size,
                              hipStream_t stream) {
    (void)in_sizes; (void)n_in; (void)out_size; (void)ws_size;

    const float* x     = (const float*)d_in[0];   // [8192,512]
    const float* h0    = (const float*)d_in[1];   // [4,768]
    const float* w_ih0 = (const float*)d_in[2];   // [2,2304,512]
    const float* w_hh0 = (const float*)d_in[3];   // [2,2304,768]
    const float* b_ih0 = (const float*)d_in[4];   // [2,2304]
    const float* b_hh0 = (const float*)d_in[5];
    const float* w_ih1 = (const float*)d_in[6];   // [2,2304,1536]
    const float* w_hh1 = (const float*)d_in[7];
    const float* b_ih1 = (const float*)d_in[8];
    const float* b_hh1 = (const float*)d_in[9];
    const float* fc_w  = (const float*)d_in[10];  // [256,1536]
    const float* fc_b  = (const float*)d_in[11];  // [256]
    float* out = (float*)d_out;

    char* ws = (char*)d_ws;
    // Exchange pair buffers (tags must start 0): 2*2*768*8 B = 24 KiB each.
    unsigned long long* exch0 = (unsigned long long*)(ws + 4096);
    unsigned long long* exch1 = (unsigned long long*)(ws + 4096 + 24576);
    float* Gi    = (float*)(ws + 65536);           // [8192][4608] fp32 = 144 MiB
    size_t gi_bytes = (size_t)T_STEPS * NDR * sizeof(float);
    float* Hout  = (float*)(ws + 65536 + gi_bytes); // [8192][2][768] = 48 MiB

    hipMemsetAsync(ws, 0, 65536, stream);

    dim3 ggrid(NDR / 128, T_STEPS / 128);  // (36, 64)

    // Phase 1: Gi0 = x @ w_ih0^T + b_ih0
    gemm_xwt<<<ggrid, 256, 0, stream>>>(x, w_ih0, b_ih0, Gi, T_STEPS, NDR, 512);
    // Phase 2: layer-0 recurrence, store all h0[t]
    gru_rec<<<NWG, 256, 0, stream>>>(Gi, w_hh0, b_hh0, h0, exch0, Hout);
    // Phase 3: Gi1 = concat_h0 @ w_ih1^T + b_ih1
    gemm_xwt<<<ggrid, 256, 0, stream>>>(Hout, w_ih1, b_ih1, Gi, T_STEPS, NDR, HC);
    // Phase 4: layer-1 recurrence
    gru_rec<<<NWG, 256, 0, stream>>>(Gi, w_hh1, b_hh1, h0 + 2 * HDIM, exch1, Hout);
    // Phase 5: y = sigmoid(fc_w @ h_last + fc_b)
    fc_sig<<<256, 64, 0, stream>>>(Hout + (size_t)(T_STEPS - 1) * HC,
                                   fc_w, fc_b, out);
}

// Round 6
// 75920.544 us; speedup vs baseline: 1.1351x; 1.1351x over previous
//
#include <hip/hip_runtime.h>
#include <cstdint>

#define T_STEPS 8192
#define HDIM    768
#define G3      2304   // 3*H
#define NDR     4608   // 2*3*H
#define HC      1536   // 2*H
#define GPD     96     // workgroups per direction per layer
#define NWG     384    // 192 L0 + 192 L1
#define RING_D  64     // ring depth (slots)
#define BP_MARG 48     // back-pressure margin (checked every 8 steps)
#define PSTRIDE 16     // prog padding (ints) -> 64 B per entry

// ---------------------------------------------------------------------------
// GEMM: C[m][n] = sum_k X[m][k] * W[n][k] + bias[n]   (for Gi0 only)
// ---------------------------------------------------------------------------
__global__ __launch_bounds__(256)
void gemm_xwt(const float* __restrict__ X, const float* __restrict__ W,
              const float* __restrict__ bias, float* __restrict__ C,
              int M, int N, int K) {
    __shared__ float As[16][132];
    __shared__ float Bs[16][132];
    const int tid = threadIdx.x;
    const int m0 = blockIdx.y * 128;
    const int n0 = blockIdx.x * 128;
    const int tm = tid >> 4;
    const int tn = tid & 15;
    float acc[8][8] = {};
    for (int k0 = 0; k0 < K; k0 += 16) {
        #pragma unroll
        for (int l = 0; l < 2; ++l) {
            int idx = l * 256 + tid;
            int row = idx >> 2;
            int kc  = (idx & 3) << 2;
            float4 a = *(const float4*)(X + (size_t)(m0 + row) * K + k0 + kc);
            As[kc + 0][row] = a.x; As[kc + 1][row] = a.y;
            As[kc + 2][row] = a.z; As[kc + 3][row] = a.w;
            float4 b = *(const float4*)(W + (size_t)(n0 + row) * K + k0 + kc);
            Bs[kc + 0][row] = b.x; Bs[kc + 1][row] = b.y;
            Bs[kc + 2][row] = b.z; Bs[kc + 3][row] = b.w;
        }
        __syncthreads();
        #pragma unroll
        for (int k = 0; k < 16; ++k) {
            float4 a0 = *(const float4*)&As[k][tm * 8];
            float4 a1 = *(const float4*)&As[k][tm * 8 + 4];
            float4 b0 = *(const float4*)&Bs[k][tn * 8];
            float4 b1 = *(const float4*)&Bs[k][tn * 8 + 4];
            float av[8] = {a0.x, a0.y, a0.z, a0.w, a1.x, a1.y, a1.z, a1.w};
            float bv[8] = {b0.x, b0.y, b0.z, b0.w, b1.x, b1.y, b1.z, b1.w};
            #pragma unroll
            for (int i = 0; i < 8; ++i)
                #pragma unroll
                for (int j = 0; j < 8; ++j)
                    acc[i][j] = fmaf(av[i], bv[j], acc[i][j]);
        }
        __syncthreads();
    }
    float bfrag[8];
    #pragma unroll
    for (int j = 0; j < 8; ++j) bfrag[j] = bias[n0 + tn * 8 + j];
    #pragma unroll
    for (int i = 0; i < 8; ++i) {
        float* cp = C + (size_t)(m0 + tm * 8 + i) * N + n0 + tn * 8;
        float4 o0, o1;
        o0.x = acc[i][0] + bfrag[0]; o0.y = acc[i][1] + bfrag[1];
        o0.z = acc[i][2] + bfrag[2]; o0.w = acc[i][3] + bfrag[3];
        o1.x = acc[i][4] + bfrag[4]; o1.y = acc[i][5] + bfrag[5];
        o1.z = acc[i][6] + bfrag[6]; o1.w = acc[i][7] + bfrag[7];
        *(float4*)(cp + 0) = o0;
        *(float4*)(cp + 4) = o1;
    }
}

// ---------------------------------------------------------------------------
// Fused 2-layer GRU recurrence. 384 WGs:
//   bid <  192: L0 role — R4's proven structure; publishes h0[t] into a
//               depth-64 tagged ring (triplicated: copy A for L0 clique,
//               B0/B1 for L1 per-direction; keeps pollers/line ~192).
//   bid >= 192: L1 role — polls ring copy B_d (both dirs, 1536 vals) +
//               own 2-deep h1 exchange; w_hh1 fp32 + w_ih1 bf16 in
//               registers; 32 partial dots (r,z merged; n split ih/hh).
// Back-pressure: L1 WG w stores prog[w] = t+1 each step; L0 poll lanes
// check prog > t-48 every 8th step (ring depth 64 -> margin 8 safe).
// Pair protocol: 8-B (fp32 ‖ tag) relaxed agent atomics, as R3/R4.
// ---------------------------------------------------------------------------
__device__ __forceinline__ float dot4(float4 a, float4 b) {
    return a.x * b.x + a.y * b.y + a.z * b.z + a.w * b.w;
}
__device__ __forceinline__ float sigf(float x) {
    return 1.0f / (1.0f + expf(-x));
}
__device__ __forceinline__ unsigned f2bf(float f) {
    unsigned u = __float_as_uint(f);
    return (u + 0x7fffu + ((u >> 16) & 1u)) >> 16;   // RNE
}
__device__ __forceinline__ float bf_lo(unsigned u) {
    return __uint_as_float(u << 16);
}
__device__ __forceinline__ float bf_hi(unsigned u) {
    return __uint_as_float(u & 0xffff0000u);
}

__global__ __launch_bounds__(256, 2)
void gru_fused(const float* __restrict__ Gi,    // [T][2][2304] layer-0 input gates
               const float* __restrict__ whh0,  // [2][2304][768]
               const float* __restrict__ bhh0,  // [2][2304]
               const float* __restrict__ wih1,  // [2][2304][1536]
               const float* __restrict__ whh1,  // [2][2304][768]
               const float* __restrict__ bih1,  // [2][2304]
               const float* __restrict__ bhh1,  // [2][2304]
               const float* __restrict__ h0,    // [4][768]
               unsigned long long* __restrict__ ring, // [3][RING_D][1536]
               unsigned long long* __restrict__ ex1,  // [2][2][768]
               int* __restrict__ prog,          // [192 * PSTRIDE]
               float* __restrict__ hlast) {     // [1536]
    const int tid  = threadIdx.x;
    const int lane = tid & 63;
    const int wave = tid >> 6;
    const int bid  = blockIdx.x;

    __shared__ float part[32][68];
    __shared__ float gsum[32];
    __shared__ float hsh[768];
    __shared__ float xsh[1536];
    __shared__ float bh[24];
    __shared__ float gi_s[24];

    if (bid < 192) {
        // ================= Layer-0 role (R4 structure + ring) =================
        const int d  = bid / GPD;
        const int j0 = (bid % GPD) * 8;
        if (tid < 24)
            bh[tid] = bhh0[d * G3 + (tid >> 3) * 768 + j0 + (tid & 7)];

        float4 w[6][3];
        #pragma unroll
        for (int m = 0; m < 6; ++m) {
            int dot = wave + 4 * m;
            const float* wrow = whh0 + (size_t)d * G3 * HDIM
                + (size_t)((dot >> 3) * 768 + j0 + (dot & 7)) * HDIM;
            #pragma unroll
            for (int i = 0; i < 3; ++i)
                w[m][i] = *(const float4*)(wrow + i * 256 + lane * 4);
        }
        __syncthreads();

        for (int t = 0; t < T_STEPS; ++t) {
            float giv = 0.0f;
            if (tid < 24)
                giv = Gi[((size_t)t * 2 + d) * G3 + (tid >> 3) * 768 + j0 + (tid & 7)];

            if (tid < 96) {
                float hv[8];
                if (t == 0) {
                    const float* src = h0 + d * 768 + tid * 8;
                    #pragma unroll
                    for (int i = 0; i < 8; ++i) hv[i] = src[i];
                } else {
                    const unsigned long long* src = ring
                        + (size_t)((t - 1) & (RING_D - 1)) * HC + d * 768 + tid * 8;
                    const bool need_bp = ((t & 7) == 0);
                    unsigned long long v[8];
                    bool ok;
                    do {
                        #pragma unroll
                        for (int i = 0; i < 8; ++i)
                            v[i] = __hip_atomic_load(src + i, __ATOMIC_RELAXED,
                                                     __HIP_MEMORY_SCOPE_AGENT);
                        ok = true;
                        #pragma unroll
                        for (int i = 0; i < 8; ++i)
                            ok &= ((unsigned)v[i] >= (unsigned)t);
                        if (need_bp) {
                            int p0 = __hip_atomic_load(prog + tid * PSTRIDE,
                                        __ATOMIC_RELAXED, __HIP_MEMORY_SCOPE_AGENT);
                            int p1 = __hip_atomic_load(prog + (tid + 96) * PSTRIDE,
                                        __ATOMIC_RELAXED, __HIP_MEMORY_SCOPE_AGENT);
                            ok &= (p0 > t - BP_MARG) && (p1 > t - BP_MARG);
                        }
                    } while (!ok);
                    #pragma unroll
                    for (int i = 0; i < 8; ++i)
                        hv[i] = __uint_as_float((unsigned)(v[i] >> 32));
                }
                #pragma unroll
                for (int i = 0; i < 8; ++i) hsh[tid * 8 + i] = hv[i];
            }
            __syncthreads();

            float4 h4[3];
            #pragma unroll
            for (int i = 0; i < 3; ++i)
                h4[i] = *(const float4*)&hsh[i * 256 + lane * 4];
            #pragma unroll
            for (int m = 0; m < 6; ++m)
                part[wave + 4 * m][lane] =
                    dot4(w[m][0], h4[0]) + dot4(w[m][1], h4[1]) + dot4(w[m][2], h4[2]);
            if (tid < 24) gi_s[tid] = giv;
            __syncthreads();

            if (tid < 192) {
                int dot = tid >> 3, o = tid & 7;
                const float* p = &part[dot][o * 8];
                float4 p0 = *(const float4*)(p + 0);
                float4 p1 = *(const float4*)(p + 4);
                float s = (p0.x + p0.y + p0.z + p0.w) + (p1.x + p1.y + p1.z + p1.w);
                s += __shfl_xor(s, 1);
                s += __shfl_xor(s, 2);
                s += __shfl_xor(s, 4);
                if (o == 0) gsum[dot] = s;
            }
            __syncthreads();

            if (tid < 8) {
                float hpv = hsh[j0 + tid];
                float r = sigf(gi_s[tid]     + gsum[tid]     + bh[tid]);
                float z = sigf(gi_s[8 + tid] + gsum[8 + tid] + bh[8 + tid]);
                float n = tanhf(gi_s[16 + tid] + r * (gsum[16 + tid] + bh[16 + tid]));
                float hn = (1.0f - z) * n + z * hpv;
                unsigned long long pair =
                    ((unsigned long long)__float_as_uint(hn) << 32)
                    | (unsigned long long)(unsigned)(t + 1);
                size_t off = (size_t)(t & (RING_D - 1)) * HC + d * 768 + j0 + tid;
                const size_t cpy = (size_t)RING_D * HC;
                __hip_atomic_store(ring + off, pair, __ATOMIC_RELAXED,
                                   __HIP_MEMORY_SCOPE_AGENT);          // copy A (L0)
                __hip_atomic_store(ring + cpy + off, pair, __ATOMIC_RELAXED,
                                   __HIP_MEMORY_SCOPE_AGENT);          // copy B0 (L1 d=0)
                __hip_atomic_store(ring + 2 * cpy + off, pair, __ATOMIC_RELAXED,
                                   __HIP_MEMORY_SCOPE_AGENT);          // copy B1 (L1 d=1)
            }
        }
    } else {
        // ================= Layer-1 role =================
        const int w1 = bid - 192;
        const int d  = w1 / GPD;
        const int j0 = (w1 % GPD) * 8;
        unsigned long long* myring = ring + (size_t)(1 + d) * RING_D * HC;

        // Weights: 32 dots per WG, dot = wave + 4*m (m<8); kind = m>>1
        // (0:r merged, 1:z merged, 2:n_ih, 3:n_hh); row8 = wave + 4*(m&1).
        float4 wh[6][3];     // kinds 0,1,3 -> whh1 fp32
        uint2  wiu[6][6];    // kinds 0,1,2 -> wih1 bf16-packed
        #pragma unroll
        for (int m = 0; m < 8; ++m) {
            const int kind = m >> 1;
            const int row8 = wave + 4 * (m & 1);
            if (kind != 2) {
                const int mh = (m < 4) ? m : m - 2;
                const int g = (kind == 3) ? 2 : kind;
                const float* wr = whh1 + (size_t)d * G3 * HDIM
                    + (size_t)(g * 768 + j0 + row8) * HDIM;
                #pragma unroll
                for (int i = 0; i < 3; ++i)
                    wh[mh][i] = *(const float4*)(wr + i * 256 + lane * 4);
            }
            if (kind != 3) {
                const float* wr = wih1 + (size_t)d * G3 * HC
                    + (size_t)(kind * 768 + j0 + row8) * HC;
                #pragma unroll
                for (int i = 0; i < 6; ++i) {
                    float4 f = *(const float4*)(wr + i * 256 + lane * 4);
                    wiu[m][i].x = f2bf(f.x) | (f2bf(f.y) << 16);
                    wiu[m][i].y = f2bf(f.z) | (f2bf(f.w) << 16);
                }
            }
        }

        float brz_r = 0.f, brz_z = 0.f, bni = 0.f, bnh = 0.f, hprev = 0.f;
        if (tid < 8) {
            int row = j0 + tid;
            brz_r = bih1[d * G3 + row]        + bhh1[d * G3 + row];
            brz_z = bih1[d * G3 + 768 + row]  + bhh1[d * G3 + 768 + row];
            bni   = bih1[d * G3 + 1536 + row];
            bnh   = bhh1[d * G3 + 1536 + row];
            hprev = h0[(2 + d) * 768 + row];
        }

        for (int t = 0; t < T_STEPS; ++t) {
            if (tid < 192) {
                // poll ring copy B_d, slot t, both dirs concat (1536 pairs)
                const unsigned long long* src =
                    myring + (size_t)(t & (RING_D - 1)) * HC + tid * 8;
                unsigned long long v[8];
                bool ok;
                do {
                    #pragma unroll
                    for (int i = 0; i < 8; ++i)
                        v[i] = __hip_atomic_load(src + i, __ATOMIC_RELAXED,
                                                 __HIP_MEMORY_SCOPE_AGENT);
                    ok = true;
                    #pragma unroll
                    for (int i = 0; i < 8; ++i)
                        ok &= ((unsigned)v[i] >= (unsigned)(t + 1));
                } while (!ok);
                #pragma unroll
                for (int i = 0; i < 8; ++i)
                    xsh[tid * 8 + i] = __uint_as_float((unsigned)(v[i] >> 32));
            } else {
                const int l3 = tid - 192;
                float hv[12];
                if (t == 0) {
                    const float* src = h0 + (2 + d) * 768 + l3 * 12;
                    #pragma unroll
                    for (int i = 0; i < 12; ++i) hv[i] = src[i];
                } else {
                    const unsigned long long* src =
                        ex1 + (size_t)((((t - 1) & 1) * 2 + d)) * 768 + l3 * 12;
                    unsigned long long v[12];
                    bool ok;
                    do {
                        #pragma unroll
                        for (int i = 0; i < 12; ++i)
                            v[i] = __hip_atomic_load(src + i, __ATOMIC_RELAXED,
                                                     __HIP_MEMORY_SCOPE_AGENT);
                        ok = true;
                        #pragma unroll
                        for (int i = 0; i < 12; ++i)
                            ok &= ((unsigned)v[i] >= (unsigned)t);
                    } while (!ok);
                    #pragma unroll
                    for (int i = 0; i < 12; ++i)
                        hv[i] = __uint_as_float((unsigned)(v[i] >> 32));
                }
                #pragma unroll
                for (int i = 0; i < 12; ++i) hsh[l3 * 12 + i] = hv[i];
            }
            __syncthreads();
            if (tid == 0)
                __hip_atomic_store(prog + w1 * PSTRIDE, t + 1, __ATOMIC_RELAXED,
                                   __HIP_MEMORY_SCOPE_AGENT);

            float4 h4[3];
            #pragma unroll
            for (int i = 0; i < 3; ++i)
                h4[i] = *(const float4*)&hsh[i * 256 + lane * 4];
            float4 x4[6];
            #pragma unroll
            for (int i = 0; i < 6; ++i)
                x4[i] = *(const float4*)&xsh[i * 256 + lane * 4];

            #pragma unroll
            for (int m = 0; m < 8; ++m) {
                const int kind = m >> 1;
                float s = 0.f;
                if (kind != 2) {
                    const int mh = (m < 4) ? m : m - 2;
                    s += dot4(wh[mh][0], h4[0]) + dot4(wh[mh][1], h4[1])
                       + dot4(wh[mh][2], h4[2]);
                }
                if (kind != 3) {
                    #pragma unroll
                    for (int i = 0; i < 6; ++i) {
                        uint2 u = wiu[m][i];
                        s = fmaf(bf_lo(u.x), x4[i].x,
                            fmaf(bf_hi(u.x), x4[i].y,
                            fmaf(bf_lo(u.y), x4[i].z,
                            fmaf(bf_hi(u.y), x4[i].w, s))));
                    }
                }
                part[wave + 4 * m][lane] = s;
            }
            __syncthreads();

            {   // 256 threads reduce 32 dots, 8 threads each
                int dot = tid >> 3, o = tid & 7;
                const float* p = &part[dot][o * 8];
                float4 p0 = *(const float4*)(p + 0);
                float4 p1 = *(const float4*)(p + 4);
                float s = (p0.x + p0.y + p0.z + p0.w) + (p1.x + p1.y + p1.z + p1.w);
                s += __shfl_xor(s, 1);
                s += __shfl_xor(s, 2);
                s += __shfl_xor(s, 4);
                if (o == 0) gsum[dot] = s;
            }
            __syncthreads();

            if (tid < 8) {
                float r = sigf(gsum[tid]      + brz_r);
                float z = sigf(gsum[8 + tid]  + brz_z);
                float n = tanhf(gsum[16 + tid] + bni + r * (gsum[24 + tid] + bnh));
                float hn = (1.0f - z) * n + z * hprev;
                hprev = hn;
                unsigned long long pair =
                    ((unsigned long long)__float_as_uint(hn) << 32)
                    | (unsigned long long)(unsigned)(t + 1);
                __hip_atomic_store(
                    ex1 + (size_t)(((t & 1) * 2 + d)) * 768 + j0 + tid, pair,
                    __ATOMIC_RELAXED, __HIP_MEMORY_SCOPE_AGENT);
                if (t == T_STEPS - 1)
                    hlast[d * 768 + j0 + tid] = hn;
            }
        }
    }
}

// ---------------------------------------------------------------------------
// Final FC + sigmoid
// ---------------------------------------------------------------------------
__global__ __launch_bounds__(64)
void fc_sig(const float* __restrict__ hin, const float* __restrict__ fw,
            const float* __restrict__ fb, float* __restrict__ out) {
    const int lane = threadIdx.x;
    const int row  = blockIdx.x;
    const float* wr = fw + (size_t)row * HC;
    float acc = 0.0f;
    #pragma unroll
    for (int i = 0; i < 6; ++i) {
        float4 w4 = *(const float4*)(wr  + i * 256 + lane * 4);
        float4 h4 = *(const float4*)(hin + i * 256 + lane * 4);
        acc += dot4(w4, h4);
    }
    #pragma unroll
    for (int s = 1; s < 64; s <<= 1) acc += __shfl_xor(acc, s);
    if (lane == 0) out[row] = sigf(acc + fb[row]);
}

// ---------------------------------------------------------------------------
extern "C" void kernel_launch(void* const* d_in, const int* in_sizes, int n_in,
                              void* d_out, int out_size, void* d_ws, size_t ws_size,
                              hipStream_t stream) {
    (void)in_sizes; (void)n_in; (void)out_size; (void)ws_size;

    const float* x     = (const float*)d_in[0];
    const float* h0    = (const float*)d_in[1];
    const float* w_ih0 = (const float*)d_in[2];
    const float* w_hh0 = (const float*)d_in[3];
    const float* b_ih0 = (const float*)d_in[4];
    const float* b_hh0 = (const float*)d_in[5];
    const float* w_ih1 = (const float*)d_in[6];
    const float* w_hh1 = (const float*)d_in[7];
    const float* b_ih1 = (const float*)d_in[8];
    const float* b_hh1 = (const float*)d_in[9];
    const float* fc_w  = (const float*)d_in[10];
    const float* fc_b  = (const float*)d_in[11];
    float* out = (float*)d_out;

    char* ws = (char*)d_ws;
    // Layout: ring (3 copies x 64 x 1536 pairs = 2,359,296 B) | ex1 24,576 B
    //         | prog 12,288 B | hlast 6,144 B | pad | Gi at 4 MiB.
    unsigned long long* ring = (unsigned long long*)ws;
    unsigned long long* ex1  = (unsigned long long*)(ws + 2359296);
    int*   prog  = (int*)(ws + 2359296 + 24576);
    float* hlast = (float*)(ws + 2359296 + 24576 + 12288);
    float* Gi    = (float*)(ws + 4194304);   // [8192][4608] fp32 = 144 MiB

    hipMemsetAsync(ws, 0, 2359296 + 24576 + 12288, stream);

    // Phase 1: Gi0 = x @ w_ih0^T + b_ih0
    dim3 ggrid(NDR / 128, T_STEPS / 128);
    gemm_xwt<<<ggrid, 256, 0, stream>>>(x, w_ih0, b_ih0, Gi, T_STEPS, NDR, 512);
    // Phase 2: fused two-layer recurrence (L1 pipelined one step behind L0)
    gru_fused<<<NWG, 256, 0, stream>>>(Gi, w_hh0, b_hh0, w_ih1, w_hh1,
                                       b_ih1, b_hh1, h0, ring, ex1, prog, hlast);
    // Phase 3: y = sigmoid(fc_w @ h1_last + fc_b)
    fc_sig<<<256, 64, 0, stream>>>(hlast, fc_w, fc_b, out);
}

// Round 7
// 65530.017 us; speedup vs baseline: 1.3151x; 1.1586x over previous
//
#include <hip/hip_runtime.h>
#include <cstdint>

#define T_STEPS 8192
#define HDIM    768
#define G3      2304   // 3*H
#define NDR     4608   // 2*3*H
#define HC      1536   // 2*H
#define GPD     96     // workgroups per direction per layer
#define NWG     384    // 192 L0 + 192 L1
#define RING_D  64     // ring depth (slots)
#define LAG     24     // enforced L1 lag (steps); < BP_MARG
#define BP_MARG 48     // back-pressure margin (checked every 8 steps)
#define PSTRIDE 16     // prog padding (ints) -> 64 B per entry

// ---------------------------------------------------------------------------
// GEMM: C[m][n] = sum_k X[m][k] * W[n][k] + bias[n]   (Gi0 only)
// ---------------------------------------------------------------------------
__global__ __launch_bounds__(256)
void gemm_xwt(const float* __restrict__ X, const float* __restrict__ W,
              const float* __restrict__ bias, float* __restrict__ C,
              int M, int N, int K) {
    __shared__ float As[16][132];
    __shared__ float Bs[16][132];
    const int tid = threadIdx.x;
    const int m0 = blockIdx.y * 128;
    const int n0 = blockIdx.x * 128;
    const int tm = tid >> 4;
    const int tn = tid & 15;
    float acc[8][8] = {};
    for (int k0 = 0; k0 < K; k0 += 16) {
        #pragma unroll
        for (int l = 0; l < 2; ++l) {
            int idx = l * 256 + tid;
            int row = idx >> 2;
            int kc  = (idx & 3) << 2;
            float4 a = *(const float4*)(X + (size_t)(m0 + row) * K + k0 + kc);
            As[kc + 0][row] = a.x; As[kc + 1][row] = a.y;
            As[kc + 2][row] = a.z; As[kc + 3][row] = a.w;
            float4 b = *(const float4*)(W + (size_t)(n0 + row) * K + k0 + kc);
            Bs[kc + 0][row] = b.x; Bs[kc + 1][row] = b.y;
            Bs[kc + 2][row] = b.z; Bs[kc + 3][row] = b.w;
        }
        __syncthreads();
        #pragma unroll
        for (int k = 0; k < 16; ++k) {
            float4 a0 = *(const float4*)&As[k][tm * 8];
            float4 a1 = *(const float4*)&As[k][tm * 8 + 4];
            float4 b0 = *(const float4*)&Bs[k][tn * 8];
            float4 b1 = *(const float4*)&Bs[k][tn * 8 + 4];
            float av[8] = {a0.x, a0.y, a0.z, a0.w, a1.x, a1.y, a1.z, a1.w};
            float bv[8] = {b0.x, b0.y, b0.z, b0.w, b1.x, b1.y, b1.z, b1.w};
            #pragma unroll
            for (int i = 0; i < 8; ++i)
                #pragma unroll
                for (int j = 0; j < 8; ++j)
                    acc[i][j] = fmaf(av[i], bv[j], acc[i][j]);
        }
        __syncthreads();
    }
    float bfrag[8];
    #pragma unroll
    for (int j = 0; j < 8; ++j) bfrag[j] = bias[n0 + tn * 8 + j];
    #pragma unroll
    for (int i = 0; i < 8; ++i) {
        float* cp = C + (size_t)(m0 + tm * 8 + i) * N + n0 + tn * 8;
        float4 o0, o1;
        o0.x = acc[i][0] + bfrag[0]; o0.y = acc[i][1] + bfrag[1];
        o0.z = acc[i][2] + bfrag[2]; o0.w = acc[i][3] + bfrag[3];
        o1.x = acc[i][4] + bfrag[4]; o1.y = acc[i][5] + bfrag[5];
        o1.z = acc[i][6] + bfrag[6]; o1.w = acc[i][7] + bfrag[7];
        *(float4*)(cp + 0) = o0;
        *(float4*)(cp + 4) = o1;
    }
}

// ---------------------------------------------------------------------------
// Fused 2-layer GRU. 384 WGs:
//  bid<192 : L0 — exact R4 structure (2-deep own exchange ex0) + ONE extra
//            pair store into a depth-64 ring for L1 + backpressure (prog,
//            margin 48, checked every 8 steps).
//  bid>=192: L1 — enforced LAG=24 behind L0 (armed at start, re-armed every
//            64 steps), so ring reads are single-shot (no retry storm).
//            Own h1 exchange ex1 polls hot (R4 pattern); ring-read latency
//            hidden behind that poll. w_hh1 fp32 + w_ih1 bf16 in registers.
// Pair protocol throughout: 8-B (fp32 ‖ step tag) relaxed agent atomics.
// ---------------------------------------------------------------------------
__device__ __forceinline__ float dot4(float4 a, float4 b) {
    return a.x * b.x + a.y * b.y + a.z * b.z + a.w * b.w;
}
__device__ __forceinline__ float sigf(float x) {
    return 1.0f / (1.0f + expf(-x));
}
__device__ __forceinline__ unsigned f2bf(float f) {
    unsigned u = __float_as_uint(f);
    return (u + 0x7fffu + ((u >> 16) & 1u)) >> 16;   // RNE
}
__device__ __forceinline__ float bf_lo(unsigned u) {
    return __uint_as_float(u << 16);
}
__device__ __forceinline__ float bf_hi(unsigned u) {
    return __uint_as_float(u & 0xffff0000u);
}
__device__ __forceinline__ unsigned long long ld_pair(
        const unsigned long long* p) {
    return __hip_atomic_load(p, __ATOMIC_RELAXED, __HIP_MEMORY_SCOPE_AGENT);
}
__device__ __forceinline__ void st_pair(unsigned long long* p,
                                        unsigned long long v) {
    __hip_atomic_store(p, v, __ATOMIC_RELAXED, __HIP_MEMORY_SCOPE_AGENT);
}

__global__ __launch_bounds__(256, 2)
void gru_fused(const float* __restrict__ Gi,    // [T][2][2304]
               const float* __restrict__ whh0,  // [2][2304][768]
               const float* __restrict__ bhh0,  // [2][2304]
               const float* __restrict__ wih1,  // [2][2304][1536]
               const float* __restrict__ whh1,  // [2][2304][768]
               const float* __restrict__ bih1,  // [2][2304]
               const float* __restrict__ bhh1,  // [2][2304]
               const float* __restrict__ h0,    // [4][768]
               unsigned long long* __restrict__ ex0,  // [2 par][2 dir][768]
               unsigned long long* __restrict__ ring, // [RING_D][1536]
               unsigned long long* __restrict__ ex1,  // [2 par][2 dir][768]
               int* __restrict__ prog,          // [192 * PSTRIDE]
               float* __restrict__ hlast) {     // [1536]
    const int tid  = threadIdx.x;
    const int lane = tid & 63;
    const int wave = tid >> 6;
    const int bid  = blockIdx.x;

    __shared__ float part[32][68];
    __shared__ float gsum[32];
    __shared__ float hsh[768];
    __shared__ float xsh[1536];
    __shared__ float bh[24];
    __shared__ float gi_s[24];

    if (bid < 192) {
        // ========================= Layer-0 role =========================
        const int d  = bid / GPD;
        const int j0 = (bid % GPD) * 8;
        if (tid < 24)
            bh[tid] = bhh0[d * G3 + (tid >> 3) * 768 + j0 + (tid & 7)];

        float4 w[6][3];
        #pragma unroll
        for (int m = 0; m < 6; ++m) {
            int dot = wave + 4 * m;
            const float* wrow = whh0 + (size_t)d * G3 * HDIM
                + (size_t)((dot >> 3) * 768 + j0 + (dot & 7)) * HDIM;
            #pragma unroll
            for (int i = 0; i < 3; ++i)
                w[m][i] = *(const float4*)(wrow + i * 256 + lane * 4);
        }
        __syncthreads();

        for (int t = 0; t < T_STEPS; ++t) {
            float giv = 0.0f;
            if (tid < 24)
                giv = Gi[((size_t)t * 2 + d) * G3 + (tid >> 3) * 768 + j0 + (tid & 7)];

            if (tid < 96) {
                float hv[8];
                if (t == 0) {
                    const float* src = h0 + d * 768 + tid * 8;
                    #pragma unroll
                    for (int i = 0; i < 8; ++i) hv[i] = src[i];
                } else {
                    const unsigned long long* src = ex0
                        + (size_t)((((t - 1) & 1) * 2 + d)) * 768 + tid * 8;
                    const bool need_bp = ((t & 7) == 0);
                    unsigned long long v[8];
                    bool ok;
                    do {
                        #pragma unroll
                        for (int i = 0; i < 8; ++i) v[i] = ld_pair(src + i);
                        ok = true;
                        #pragma unroll
                        for (int i = 0; i < 8; ++i)
                            ok &= ((unsigned)v[i] >= (unsigned)t);
                        if (need_bp) {
                            int p0 = __hip_atomic_load(prog + tid * PSTRIDE,
                                        __ATOMIC_RELAXED, __HIP_MEMORY_SCOPE_AGENT);
                            int p1 = __hip_atomic_load(prog + (tid + 96) * PSTRIDE,
                                        __ATOMIC_RELAXED, __HIP_MEMORY_SCOPE_AGENT);
                            ok &= (p0 > t - BP_MARG) && (p1 > t - BP_MARG);
                        }
                    } while (!ok);
                    #pragma unroll
                    for (int i = 0; i < 8; ++i)
                        hv[i] = __uint_as_float((unsigned)(v[i] >> 32));
                }
                #pragma unroll
                for (int i = 0; i < 8; ++i) hsh[tid * 8 + i] = hv[i];
            }
            __syncthreads();

            float4 h4[3];
            #pragma unroll
            for (int i = 0; i < 3; ++i)
                h4[i] = *(const float4*)&hsh[i * 256 + lane * 4];
            #pragma unroll
            for (int m = 0; m < 6; ++m)
                part[wave + 4 * m][lane] =
                    dot4(w[m][0], h4[0]) + dot4(w[m][1], h4[1]) + dot4(w[m][2], h4[2]);
            if (tid < 24) gi_s[tid] = giv;
            __syncthreads();

            if (tid < 192) {
                int dot = tid >> 3, o = tid & 7;
                const float* p = &part[dot][o * 8];
                float4 p0 = *(const float4*)(p + 0);
                float4 p1 = *(const float4*)(p + 4);
                float s = (p0.x + p0.y + p0.z + p0.w) + (p1.x + p1.y + p1.z + p1.w);
                s += __shfl_xor(s, 1);
                s += __shfl_xor(s, 2);
                s += __shfl_xor(s, 4);
                if (o == 0) gsum[dot] = s;
            }
            __syncthreads();

            if (tid < 8) {
                float hpv = hsh[j0 + tid];
                float r = sigf(gi_s[tid]     + gsum[tid]     + bh[tid]);
                float z = sigf(gi_s[8 + tid] + gsum[8 + tid] + bh[8 + tid]);
                float n = tanhf(gi_s[16 + tid] + r * (gsum[16 + tid] + bh[16 + tid]));
                float hn = (1.0f - z) * n + z * hpv;
                unsigned long long pair =
                    ((unsigned long long)__float_as_uint(hn) << 32)
                    | (unsigned long long)(unsigned)(t + 1);
                st_pair(ex0 + (size_t)(((t & 1) * 2 + d)) * 768 + j0 + tid, pair);
                st_pair(ring + (size_t)(t & (RING_D - 1)) * HC + d * 768 + j0 + tid,
                        pair);
            }
        }
    } else {
        // ========================= Layer-1 role =========================
        const int w1 = bid - 192;
        const int d  = w1 / GPD;
        const int j0 = (w1 % GPD) * 8;

        // Weights: 32 dots, dot = wave + 4*m; kind = m>>1 (0:r, 1:z merged
        // ih+hh; 2:n_ih; 3:n_hh); row8 = wave + 4*(m&1); dotIdx = 8*kind+row8.
        float4 wh[6][3];     // m 0..3 (r,z hh), m 6,7 -> wh[4,5] (n hh)
        uint2  wiu[6][6];    // m 0..5 (r,z,n ih) bf16-packed
        #pragma unroll
        for (int m = 0; m < 8; ++m) {
            const int kind = m >> 1;
            const int row8 = wave + 4 * (m & 1);
            if (kind != 2) {
                const int mh = (m < 4) ? m : m - 2;
                const int g = (kind == 3) ? 2 : kind;
                const float* wr = whh1 + (size_t)d * G3 * HDIM
                    + (size_t)(g * 768 + j0 + row8) * HDIM;
                #pragma unroll
                for (int i = 0; i < 3; ++i)
                    wh[mh][i] = *(const float4*)(wr + i * 256 + lane * 4);
            }
            if (kind != 3) {
                const float* wr = wih1 + (size_t)d * G3 * HC
                    + (size_t)(kind * 768 + j0 + row8) * HC;
                #pragma unroll
                for (int i = 0; i < 6; ++i) {
                    float4 f = *(const float4*)(wr + i * 256 + lane * 4);
                    wiu[m][i].x = f2bf(f.x) | (f2bf(f.y) << 16);
                    wiu[m][i].y = f2bf(f.z) | (f2bf(f.w) << 16);
                }
            }
        }

        float brz_r = 0.f, brz_z = 0.f, bni = 0.f, bnh = 0.f, hprev = 0.f;
        if (tid < 8) {
            int row = j0 + tid;
            brz_r = bih1[d * G3 + row]        + bhh1[d * G3 + row];
            brz_z = bih1[d * G3 + 768 + row]  + bhh1[d * G3 + 768 + row];
            bni   = bih1[d * G3 + 1536 + row];
            bnh   = bhh1[d * G3 + 1536 + row];
            hprev = h0[(2 + d) * 768 + row];
        }

        // --- Arm the lag: wait until L0 has completed step LAG. ---
        {
            const unsigned long long* src = ring + (size_t)LAG * HC + tid * 6;
            bool ok;
            do {
                ok = true;
                #pragma unroll
                for (int i = 0; i < 6; ++i)
                    ok &= ((unsigned)ld_pair(src + i) >= (unsigned)(LAG + 1));
            } while (!ok);
        }

        for (int t = 0; t < T_STEPS; ++t) {
            // Issue ring reads for slot t (lag => published long ago).
            const unsigned long long* rs =
                ring + (size_t)(t & (RING_D - 1)) * HC + tid * 6;
            unsigned long long v[6];
            #pragma unroll
            for (int i = 0; i < 6; ++i) v[i] = ld_pair(rs + i);

            // Hot poll of own h1 exchange (overlaps ring-read latency).
            if (tid < 96) {
                float hv[8];
                if (t == 0) {
                    const float* src = h0 + (2 + d) * 768 + tid * 8;
                    #pragma unroll
                    for (int i = 0; i < 8; ++i) hv[i] = src[i];
                } else {
                    const unsigned long long* src = ex1
                        + (size_t)((((t - 1) & 1) * 2 + d)) * 768 + tid * 8;
                    unsigned long long u[8];
                    bool ok;
                    do {
                        #pragma unroll
                        for (int i = 0; i < 8; ++i) u[i] = ld_pair(src + i);
                        ok = true;
                        #pragma unroll
                        for (int i = 0; i < 8; ++i)
                            ok &= ((unsigned)u[i] >= (unsigned)t);
                    } while (!ok);
                    #pragma unroll
                    for (int i = 0; i < 8; ++i)
                        hv[i] = __uint_as_float((unsigned)(u[i] >> 32));
                }
                #pragma unroll
                for (int i = 0; i < 8; ++i) hsh[tid * 8 + i] = hv[i];
            }

            // Validate ring batch (rare retry), plus periodic lag re-arm.
            {
                bool ok;
                #pragma unroll
                for (int i = 0; i < 6; ++i) {
                    // first pass uses already-loaded v[]
                }
                const int target = ((t & 63) == 0)
                    ? ((t + LAG < T_STEPS) ? t + LAG : T_STEPS - 1) : -1;
                for (;;) {
                    ok = true;
                    #pragma unroll
                    for (int i = 0; i < 6; ++i)
                        ok &= ((unsigned)v[i] >= (unsigned)(t + 1));
                    if (ok && target >= 0) {
                        const unsigned long long* as =
                            ring + (size_t)(target & (RING_D - 1)) * HC + tid * 6;
                        #pragma unroll
                        for (int i = 0; i < 6; ++i)
                            ok &= ((unsigned)ld_pair(as + i) >= (unsigned)(target + 1));
                    }
                    if (ok) break;
                    #pragma unroll
                    for (int i = 0; i < 6; ++i) v[i] = ld_pair(rs + i);
                }
                #pragma unroll
                for (int i = 0; i < 6; ++i)
                    xsh[tid * 6 + i] = __uint_as_float((unsigned)(v[i] >> 32));
            }
            __syncthreads();
            if (tid == 0)
                __hip_atomic_store(prog + w1 * PSTRIDE, t + 1, __ATOMIC_RELAXED,
                                   __HIP_MEMORY_SCOPE_AGENT);

            float4 h4[3];
            #pragma unroll
            for (int i = 0; i < 3; ++i)
                h4[i] = *(const float4*)&hsh[i * 256 + lane * 4];
            float4 x4[6];
            #pragma unroll
            for (int i = 0; i < 6; ++i)
                x4[i] = *(const float4*)&xsh[i * 256 + lane * 4];

            #pragma unroll
            for (int m = 0; m < 8; ++m) {
                const int kind = m >> 1;
                float s = 0.f;
                if (kind != 2) {
                    const int mh = (m < 4) ? m : m - 2;
                    s += dot4(wh[mh][0], h4[0]) + dot4(wh[mh][1], h4[1])
                       + dot4(wh[mh][2], h4[2]);
                }
                if (kind != 3) {
                    #pragma unroll
                    for (int i = 0; i < 6; ++i) {
                        uint2 u = wiu[m][i];
                        s = fmaf(bf_lo(u.x), x4[i].x,
                            fmaf(bf_hi(u.x), x4[i].y,
                            fmaf(bf_lo(u.y), x4[i].z,
                            fmaf(bf_hi(u.y), x4[i].w, s))));
                    }
                }
                part[wave + 4 * m][lane] = s;
            }
            __syncthreads();

            {   // 256 threads reduce 32 dots, 8 threads each
                int dot = tid >> 3, o = tid & 7;
                const float* p = &part[dot][o * 8];
                float4 p0 = *(const float4*)(p + 0);
                float4 p1 = *(const float4*)(p + 4);
                float s = (p0.x + p0.y + p0.z + p0.w) + (p1.x + p1.y + p1.z + p1.w);
                s += __shfl_xor(s, 1);
                s += __shfl_xor(s, 2);
                s += __shfl_xor(s, 4);
                if (o == 0) gsum[dot] = s;
            }
            __syncthreads();

            if (tid < 8) {
                float r = sigf(gsum[tid]      + brz_r);
                float z = sigf(gsum[8 + tid]  + brz_z);
                float n = tanhf(gsum[16 + tid] + bni + r * (gsum[24 + tid] + bnh));
                float hn = (1.0f - z) * n + z * hprev;
                hprev = hn;
                unsigned long long pair =
                    ((unsigned long long)__float_as_uint(hn) << 32)
                    | (unsigned long long)(unsigned)(t + 1);
                st_pair(ex1 + (size_t)(((t & 1) * 2 + d)) * 768 + j0 + tid, pair);
                if (t == T_STEPS - 1)
                    hlast[d * 768 + j0 + tid] = hn;
            }
        }
    }
}

// ---------------------------------------------------------------------------
// Final FC + sigmoid
// ---------------------------------------------------------------------------
__global__ __launch_bounds__(64)
void fc_sig(const float* __restrict__ hin, const float* __restrict__ fw,
            const float* __restrict__ fb, float* __restrict__ out) {
    const int lane = threadIdx.x;
    const int row  = blockIdx.x;
    const float* wr = fw + (size_t)row * HC;
    float acc = 0.0f;
    #pragma unroll
    for (int i = 0; i < 6; ++i) {
        float4 w4 = *(const float4*)(wr  + i * 256 + lane * 4);
        float4 h4 = *(const float4*)(hin + i * 256 + lane * 4);
        acc += dot4(w4, h4);
    }
    #pragma unroll
    for (int s = 1; s < 64; s <<= 1) acc += __shfl_xor(acc, s);
    if (lane == 0) out[row] = sigf(acc + fb[row]);
}

// ---------------------------------------------------------------------------
extern "C" void kernel_launch(void* const* d_in, const int* in_sizes, int n_in,
                              void* d_out, int out_size, void* d_ws, size_t ws_size,
                              hipStream_t stream) {
    (void)in_sizes; (void)n_in; (void)out_size; (void)ws_size;

    const float* x     = (const float*)d_in[0];
    const float* h0    = (const float*)d_in[1];
    const float* w_ih0 = (const float*)d_in[2];
    const float* w_hh0 = (const float*)d_in[3];
    const float* b_ih0 = (const float*)d_in[4];
    const float* b_hh0 = (const float*)d_in[5];
    const float* w_ih1 = (const float*)d_in[6];
    const float* w_hh1 = (const float*)d_in[7];
    const float* b_ih1 = (const float*)d_in[8];
    const float* b_hh1 = (const float*)d_in[9];
    const float* fc_w  = (const float*)d_in[10];
    const float* fc_b  = (const float*)d_in[11];
    float* out = (float*)d_out;

    char* ws = (char*)d_ws;
    // ring 64*1536*8 = 786,432 | ex0 24,576 | ex1 24,576 | prog 12,288
    // | hlast 6,144 | Gi at 1 MiB (144 MiB)
    unsigned long long* ring = (unsigned long long*)ws;
    unsigned long long* ex0  = (unsigned long long*)(ws + 786432);
    unsigned long long* ex1  = (unsigned long long*)(ws + 786432 + 24576);
    int*   prog  = (int*)(ws + 786432 + 49152);
    float* hlast = (float*)(ws + 786432 + 49152 + 12288);
    float* Gi    = (float*)(ws + 1048576);

    hipMemsetAsync(ws, 0, 1048576, stream);

    // Phase 1: Gi0 = x @ w_ih0^T + b_ih0
    dim3 ggrid(NDR / 128, T_STEPS / 128);
    gemm_xwt<<<ggrid, 256, 0, stream>>>(x, w_ih0, b_ih0, Gi, T_STEPS, NDR, 512);
    // Phase 2: fused two-layer recurrence (L1 lag-24 pipeline)
    gru_fused<<<NWG, 256, 0, stream>>>(Gi, w_hh0, b_hh0, w_ih1, w_hh1,
                                       b_ih1, b_hh1, h0, ex0, ring, ex1,
                                       prog, hlast);
    // Phase 3: y = sigmoid(fc_w @ h1_last + fc_b)
    fc_sig<<<256, 64, 0, stream>>>(hlast, fc_w, fc_b, out);
}

// Round 8
// 53981.256 us; speedup vs baseline: 1.5965x; 1.2139x over previous
//
#include <hip/hip_runtime.h>
#include <cstdint>

#define T_STEPS 8192
#define HDIM    768
#define G3      2304   // 3*H
#define NDR     4608   // 2*3*H
#define HC      1536   // 2*H
#define GPD     96     // workgroups per direction
#define NWG     192    // 2 dirs x 96 WGs (independent cliques)
#define C_ROWS  8      // h-rows per workgroup (2 per wave)

// ---------------------------------------------------------------------------
// GEMM: C[m][n] = sum_k X[m][k] * W[n][k] + bias[n]
// X: [M,K] row-major, W: [N,K] row-major. 128x128 tile, BK=16, 256 thr, 8x8.
// ---------------------------------------------------------------------------
__global__ __launch_bounds__(256)
void gemm_xwt(const float* __restrict__ X, const float* __restrict__ W,
              const float* __restrict__ bias, float* __restrict__ C,
              int M, int N, int K) {
    __shared__ float As[16][132];
    __shared__ float Bs[16][132];
    const int tid = threadIdx.x;
    const int m0 = blockIdx.y * 128;
    const int n0 = blockIdx.x * 128;
    const int tm = tid >> 4;
    const int tn = tid & 15;
    float acc[8][8] = {};
    for (int k0 = 0; k0 < K; k0 += 16) {
        #pragma unroll
        for (int l = 0; l < 2; ++l) {
            int idx = l * 256 + tid;
            int row = idx >> 2;
            int kc  = (idx & 3) << 2;
            float4 a = *(const float4*)(X + (size_t)(m0 + row) * K + k0 + kc);
            As[kc + 0][row] = a.x; As[kc + 1][row] = a.y;
            As[kc + 2][row] = a.z; As[kc + 3][row] = a.w;
            float4 b = *(const float4*)(W + (size_t)(n0 + row) * K + k0 + kc);
            Bs[kc + 0][row] = b.x; Bs[kc + 1][row] = b.y;
            Bs[kc + 2][row] = b.z; Bs[kc + 3][row] = b.w;
        }
        __syncthreads();
        #pragma unroll
        for (int k = 0; k < 16; ++k) {
            float4 a0 = *(const float4*)&As[k][tm * 8];
            float4 a1 = *(const float4*)&As[k][tm * 8 + 4];
            float4 b0 = *(const float4*)&Bs[k][tn * 8];
            float4 b1 = *(const float4*)&Bs[k][tn * 8 + 4];
            float av[8] = {a0.x, a0.y, a0.z, a0.w, a1.x, a1.y, a1.z, a1.w};
            float bv[8] = {b0.x, b0.y, b0.z, b0.w, b1.x, b1.y, b1.z, b1.w};
            #pragma unroll
            for (int i = 0; i < 8; ++i)
                #pragma unroll
                for (int j = 0; j < 8; ++j)
                    acc[i][j] = fmaf(av[i], bv[j], acc[i][j]);
        }
        __syncthreads();
    }
    float bfrag[8];
    #pragma unroll
    for (int j = 0; j < 8; ++j) bfrag[j] = bias[n0 + tn * 8 + j];
    #pragma unroll
    for (int i = 0; i < 8; ++i) {
        float* cp = C + (size_t)(m0 + tm * 8 + i) * N + n0 + tn * 8;
        float4 o0, o1;
        o0.x = acc[i][0] + bfrag[0]; o0.y = acc[i][1] + bfrag[1];
        o0.z = acc[i][2] + bfrag[2]; o0.w = acc[i][3] + bfrag[3];
        o1.x = acc[i][4] + bfrag[4]; o1.y = acc[i][5] + bfrag[5];
        o1.z = acc[i][6] + bfrag[6]; o1.w = acc[i][7] + bfrag[7];
        *(float4*)(cp + 0) = o0;
        *(float4*)(cp + 4) = o1;
    }
}

// ---------------------------------------------------------------------------
// GRU recurrence, hybrid step (R4 poll + wave-autonomous compute).
// 192 WGs = 2 independent cliques of 96; each WG owns 8 h-rows; each of its
// 4 waves is a self-contained engine for 2 rows x 3 gates (6 dots of 768).
// Per step:
//   1. waves 0+1 (tid<96): lane i polls producer i's 8 pairs (8-B fp32‖tag,
//      relaxed agent atomics — R4-proven density of 96 pollers/line) and
//      writes h into the PARITY-staggered hsh[t&1][768] LDS buffer.
//   2. ONE __syncthreads.
//   3. every wave: 3x ds_read_b128 of h, 72 FMAs vs register weights,
//      6-value 64-lane butterfly, lanes 0/1 compute gates and publish their
//      pair + Hout. No part[] LDS, no reduce/gate phases, no more syncs.
// Parity stagger removes the hsh WAR hazard across steps (pollers at t+1
// write the other buffer; buffer reuse at t+2 is gated by our own t+1
// publish, which data-depends on our step-t reads).
// ---------------------------------------------------------------------------
__device__ __forceinline__ float sigf(float x) {
    return 1.0f / (1.0f + expf(-x));
}
__device__ __forceinline__ unsigned long long ld_pair(
        const unsigned long long* p) {
    return __hip_atomic_load(p, __ATOMIC_RELAXED, __HIP_MEMORY_SCOPE_AGENT);
}
__device__ __forceinline__ void st_pair(unsigned long long* p,
                                        unsigned long long v) {
    __hip_atomic_store(p, v, __ATOMIC_RELAXED, __HIP_MEMORY_SCOPE_AGENT);
}

__global__ __launch_bounds__(256, 1)
void gru_rec(const float* __restrict__ Gi,   // [T][2][2304]
             const float* __restrict__ whh,  // [2][2304][768]
             const float* __restrict__ bhh,  // [2][2304]
             const float* __restrict__ h0,   // [2][768] (layer slice)
             unsigned long long* __restrict__ exch, // [2 par][2 dir][768]
             float* __restrict__ Hout) {     // [T][2][768]
    const int tid  = threadIdx.x;
    const int lane = tid & 63;
    const int wave = tid >> 6;
    const int bid  = blockIdx.x;
    const int d    = bid / GPD;
    const int j0   = (bid % GPD) * C_ROWS;

    __shared__ float hsh[2][768];

    // Register-resident weights: m = g*2 + ri, row = j0 + wave + 4*ri.
    float4 w[6][3];
    #pragma unroll
    for (int g = 0; g < 3; ++g)
        #pragma unroll
        for (int ri = 0; ri < 2; ++ri) {
            const float* wrow = whh + (size_t)d * G3 * HDIM
                + (size_t)(g * 768 + j0 + wave + 4 * ri) * HDIM;
            #pragma unroll
            for (int i = 0; i < 3; ++i)
                w[g * 2 + ri][i] = *(const float4*)(wrow + i * 256 + lane * 4);
        }

    // Publishing lanes 0,1: per-row constants + initial h.
    const int myrow = j0 + wave + 4 * (lane & 1);   // meaningful for lane<2
    float bh_r = 0.f, bh_z = 0.f, bh_n = 0.f, hprev = 0.f;
    if (lane < 2) {
        bh_r  = bhh[d * G3 +        myrow];
        bh_z  = bhh[d * G3 +  768 + myrow];
        bh_n  = bhh[d * G3 + 1536 + myrow];
        hprev = h0[d * 768 + myrow];
    }

    for (int t = 0; t < T_STEPS; ++t) {
        // Gi prefetch for the 2 owned rows (in flight during the poll).
        float gi_r = 0.f, gi_z = 0.f, gi_n = 0.f;
        if (lane < 2) {
            const float* gip = Gi + ((size_t)t * 2 + d) * G3;
            gi_r = gip[        myrow];
            gi_z = gip[ 768 + myrow];
            gi_n = gip[1536 + myrow];
        }

        // --- Phase 1: poll (waves 0+1), write h into hsh[t&1] ---
        if (tid < 96) {
            float hv[8];
            if (t == 0) {
                const float* src = h0 + d * 768 + tid * 8;
                #pragma unroll
                for (int i = 0; i < 8; ++i) hv[i] = src[i];
            } else {
                const unsigned long long* src = exch
                    + (size_t)((((t - 1) & 1) * 2 + d)) * 768 + tid * 8;
                unsigned long long v[8];
                bool ok;
                do {
                    #pragma unroll
                    for (int i = 0; i < 8; ++i) v[i] = ld_pair(src + i);
                    ok = true;
                    #pragma unroll
                    for (int i = 0; i < 8; ++i)
                        ok &= ((unsigned)v[i] >= (unsigned)t);
                } while (!ok);
                #pragma unroll
                for (int i = 0; i < 8; ++i)
                    hv[i] = __uint_as_float((unsigned)(v[i] >> 32));
            }
            #pragma unroll
            for (int i = 0; i < 8; ++i) hsh[t & 1][tid * 8 + i] = hv[i];
        }
        __syncthreads();

        // --- Phase 2: wave-autonomous compute ---
        const float* hb = hsh[t & 1];
        float4 h4[3];
        #pragma unroll
        for (int i = 0; i < 3; ++i)
            h4[i] = *(const float4*)&hb[i * 256 + lane * 4];

        float S[6];
        #pragma unroll
        for (int m = 0; m < 6; ++m) {
            float s = 0.f;
            s = fmaf(w[m][0].x, h4[0].x, s); s = fmaf(w[m][0].y, h4[0].y, s);
            s = fmaf(w[m][0].z, h4[0].z, s); s = fmaf(w[m][0].w, h4[0].w, s);
            s = fmaf(w[m][1].x, h4[1].x, s); s = fmaf(w[m][1].y, h4[1].y, s);
            s = fmaf(w[m][1].z, h4[1].z, s); s = fmaf(w[m][1].w, h4[1].w, s);
            s = fmaf(w[m][2].x, h4[2].x, s); s = fmaf(w[m][2].y, h4[2].y, s);
            s = fmaf(w[m][2].z, h4[2].z, s); s = fmaf(w[m][2].w, h4[2].w, s);
            S[m] = s;
        }
        #pragma unroll
        for (int sft = 1; sft < 64; sft <<= 1) {
            #pragma unroll
            for (int m = 0; m < 6; ++m) S[m] += __shfl_xor(S[m], sft);
        }

        if (lane < 2) {
            float Sr = (lane == 0) ? S[0] : S[1];
            float Sz = (lane == 0) ? S[2] : S[3];
            float Sn = (lane == 0) ? S[4] : S[5];
            float r = sigf(gi_r + Sr + bh_r);
            float z = sigf(gi_z + Sz + bh_z);
            float n = tanhf(gi_n + r * (Sn + bh_n));
            float hn = (1.0f - z) * n + z * hprev;
            hprev = hn;
            unsigned long long pair =
                ((unsigned long long)__float_as_uint(hn) << 32)
                | (unsigned long long)(unsigned)(t + 1);
            st_pair(exch + (size_t)(((t & 1) * 2 + d)) * 768 + myrow, pair);
            Hout[((size_t)t * 2 + d) * 768 + myrow] = hn;
        }
        // no trailing __syncthreads: hsh is parity-staggered, and buffer
        // reuse at t+2 is transitively ordered behind our step-t reads.
    }
}

// ---------------------------------------------------------------------------
// Final FC + sigmoid: out[r] = sigmoid(fc_w[r] . hin + fc_b[r]); one wave/row.
// ---------------------------------------------------------------------------
__device__ __forceinline__ float dot4(float4 a, float4 b) {
    return a.x * b.x + a.y * b.y + a.z * b.z + a.w * b.w;
}

__global__ __launch_bounds__(64)
void fc_sig(const float* __restrict__ hin, const float* __restrict__ fw,
            const float* __restrict__ fb, float* __restrict__ out) {
    const int lane = threadIdx.x;
    const int row  = blockIdx.x;
    const float* wr = fw + (size_t)row * HC;
    float acc = 0.0f;
    #pragma unroll
    for (int i = 0; i < 6; ++i) {
        float4 w4 = *(const float4*)(wr  + i * 256 + lane * 4);
        float4 h4 = *(const float4*)(hin + i * 256 + lane * 4);
        acc += dot4(w4, h4);
    }
    #pragma unroll
    for (int s = 1; s < 64; s <<= 1) acc += __shfl_xor(acc, s);
    if (lane == 0) out[row] = sigf(acc + fb[row]);
}

// ---------------------------------------------------------------------------
extern "C" void kernel_launch(void* const* d_in, const int* in_sizes, int n_in,
                              void* d_out, int out_size, void* d_ws, size_t ws_size,
                              hipStream_t stream) {
    (void)in_sizes; (void)n_in; (void)out_size; (void)ws_size;

    const float* x     = (const float*)d_in[0];   // [8192,512]
    const float* h0    = (const float*)d_in[1];   // [4,768]
    const float* w_ih0 = (const float*)d_in[2];   // [2,2304,512]
    const float* w_hh0 = (const float*)d_in[3];   // [2,2304,768]
    const float* b_ih0 = (const float*)d_in[4];   // [2,2304]
    const float* b_hh0 = (const float*)d_in[5];
    const float* w_ih1 = (const float*)d_in[6];   // [2,2304,1536]
    const float* w_hh1 = (const float*)d_in[7];
    const float* b_ih1 = (const float*)d_in[8];
    const float* b_hh1 = (const float*)d_in[9];
    const float* fc_w  = (const float*)d_in[10];  // [256,1536]
    const float* fc_b  = (const float*)d_in[11];  // [256]
    float* out = (float*)d_out;

    char* ws = (char*)d_ws;
    // Exchange pair buffers (tags must start 0): 2*2*768*8 B = 24 KiB each.
    unsigned long long* exch0 = (unsigned long long*)(ws + 4096);
    unsigned long long* exch1 = (unsigned long long*)(ws + 4096 + 24576);
    float* Gi    = (float*)(ws + 65536);           // [8192][4608] fp32 = 144 MiB
    size_t gi_bytes = (size_t)T_STEPS * NDR * sizeof(float);
    float* Hout  = (float*)(ws + 65536 + gi_bytes); // [8192][2][768] = 48 MiB

    hipMemsetAsync(ws, 0, 65536, stream);

    dim3 ggrid(NDR / 128, T_STEPS / 128);  // (36, 64)

    // Phase 1: Gi0 = x @ w_ih0^T + b_ih0
    gemm_xwt<<<ggrid, 256, 0, stream>>>(x, w_ih0, b_ih0, Gi, T_STEPS, NDR, 512);
    // Phase 2: layer-0 recurrence, store all h0[t]
    gru_rec<<<NWG, 256, 0, stream>>>(Gi, w_hh0, b_hh0, h0, exch0, Hout);
    // Phase 3: Gi1 = concat_h0 @ w_ih1^T + b_ih1
    gemm_xwt<<<ggrid, 256, 0, stream>>>(Hout, w_ih1, b_ih1, Gi, T_STEPS, NDR, HC);
    // Phase 4: layer-1 recurrence
    gru_rec<<<NWG, 256, 0, stream>>>(Gi, w_hh1, b_hh1, h0 + 2 * HDIM, exch1, Hout);
    // Phase 5: y = sigmoid(fc_w @ h_last + fc_b)
    fc_sig<<<256, 64, 0, stream>>>(Hout + (size_t)(T_STEPS - 1) * HC,
                                   fc_w, fc_b, out);
}

// Round 9
// 39512.076 us; speedup vs baseline: 2.1811x; 1.3662x over previous
//
#include <hip/hip_runtime.h>
#include <cstdint>

#define T_STEPS 8192
#define HDIM    768
#define G3      2304   // 3*H
#define NDR     4608   // 2*3*H
#define HC      1536   // 2*H
#define GPD     96     // workgroups per direction
#define NWG     192    // 2 dirs x 96 WGs (independent cliques)
#define C_ROWS  8      // h-rows per workgroup (2 per wave)

// ---------------------------------------------------------------------------
// GEMM: C[m][n] = sum_k X[m][k] * W[n][k] + bias[n]
// X: [M,K] row-major, W: [N,K] row-major. 128x128 tile, BK=16, 256 thr, 8x8.
// ---------------------------------------------------------------------------
__global__ __launch_bounds__(256)
void gemm_xwt(const float* __restrict__ X, const float* __restrict__ W,
              const float* __restrict__ bias, float* __restrict__ C,
              int M, int N, int K) {
    __shared__ float As[16][132];
    __shared__ float Bs[16][132];
    const int tid = threadIdx.x;
    const int m0 = blockIdx.y * 128;
    const int n0 = blockIdx.x * 128;
    const int tm = tid >> 4;
    const int tn = tid & 15;
    float acc[8][8] = {};
    for (int k0 = 0; k0 < K; k0 += 16) {
        #pragma unroll
        for (int l = 0; l < 2; ++l) {
            int idx = l * 256 + tid;
            int row = idx >> 2;
            int kc  = (idx & 3) << 2;
            float4 a = *(const float4*)(X + (size_t)(m0 + row) * K + k0 + kc);
            As[kc + 0][row] = a.x; As[kc + 1][row] = a.y;
            As[kc + 2][row] = a.z; As[kc + 3][row] = a.w;
            float4 b = *(const float4*)(W + (size_t)(n0 + row) * K + k0 + kc);
            Bs[kc + 0][row] = b.x; Bs[kc + 1][row] = b.y;
            Bs[kc + 2][row] = b.z; Bs[kc + 3][row] = b.w;
        }
        __syncthreads();
        #pragma unroll
        for (int k = 0; k < 16; ++k) {
            float4 a0 = *(const float4*)&As[k][tm * 8];
            float4 a1 = *(const float4*)&As[k][tm * 8 + 4];
            float4 b0 = *(const float4*)&Bs[k][tn * 8];
            float4 b1 = *(const float4*)&Bs[k][tn * 8 + 4];
            float av[8] = {a0.x, a0.y, a0.z, a0.w, a1.x, a1.y, a1.z, a1.w};
            float bv[8] = {b0.x, b0.y, b0.z, b0.w, b1.x, b1.y, b1.z, b1.w};
            #pragma unroll
            for (int i = 0; i < 8; ++i)
                #pragma unroll
                for (int j = 0; j < 8; ++j)
                    acc[i][j] = fmaf(av[i], bv[j], acc[i][j]);
        }
        __syncthreads();
    }
    float bfrag[8];
    #pragma unroll
    for (int j = 0; j < 8; ++j) bfrag[j] = bias[n0 + tn * 8 + j];
    #pragma unroll
    for (int i = 0; i < 8; ++i) {
        float* cp = C + (size_t)(m0 + tm * 8 + i) * N + n0 + tn * 8;
        float4 o0, o1;
        o0.x = acc[i][0] + bfrag[0]; o0.y = acc[i][1] + bfrag[1];
        o0.z = acc[i][2] + bfrag[2]; o0.w = acc[i][3] + bfrag[3];
        o1.x = acc[i][4] + bfrag[4]; o1.y = acc[i][5] + bfrag[5];
        o1.z = acc[i][6] + bfrag[6]; o1.w = acc[i][7] + bfrag[7];
        *(float4*)(cp + 0) = o0;
        *(float4*)(cp + 4) = o1;
    }
}

// ---------------------------------------------------------------------------
// GRU recurrence, R9: R8's light compute + R4's single-transaction publish.
// 192 WGs = 2 cliques of 96; WG owns 8 h-rows; wave w computes rows
// j0+w, j0+w+4 (all 3 gates = 6 dots of 768) with register weights.
// Step: [poll 96 lanes -> hsh[t&1]] sync [all waves: 72 FMA + 36-shuffle
// butterfly; lanes 0..5 write 6 sums to gsum[wave*6+lane]] sync
// [wave-0 tid<8: gates for row j0+tid, publish all 8 pairs in ONE coalesced
// 64-B store + coalesced Hout]. Two syncs; no part[] LDS (no conflicts).
// Publish-as-one-transaction is the R8 fix: one visibility event per line.
// Overwrite-safety (2-deep parity exchange) as R4: producer reaches t+2
// only after consuming every step-t+1 line, which data-depends on every
// consumer's step-t+1 reads of the parity-t slots.
// ---------------------------------------------------------------------------
__device__ __forceinline__ float sigf(float x) {
    return 1.0f / (1.0f + expf(-x));
}
__device__ __forceinline__ unsigned long long ld_pair(
        const unsigned long long* p) {
    return __hip_atomic_load(p, __ATOMIC_RELAXED, __HIP_MEMORY_SCOPE_AGENT);
}
__device__ __forceinline__ void st_pair(unsigned long long* p,
                                        unsigned long long v) {
    __hip_atomic_store(p, v, __ATOMIC_RELAXED, __HIP_MEMORY_SCOPE_AGENT);
}

__global__ __launch_bounds__(256, 1)
void gru_rec(const float* __restrict__ Gi,   // [T][2][2304]
             const float* __restrict__ whh,  // [2][2304][768]
             const float* __restrict__ bhh,  // [2][2304]
             const float* __restrict__ h0,   // [2][768] (layer slice)
             unsigned long long* __restrict__ exch, // [2 par][2 dir][768]
             float* __restrict__ Hout) {     // [T][2][768]
    const int tid  = threadIdx.x;
    const int lane = tid & 63;
    const int wave = tid >> 6;
    const int bid  = blockIdx.x;
    const int d    = bid / GPD;
    const int j0   = (bid % GPD) * C_ROWS;

    __shared__ float hsh[2][768];
    __shared__ float gsum[24];

    // Register-resident weights: m = g*2 + ri, row = j0 + wave + 4*ri.
    float4 w[6][3];
    #pragma unroll
    for (int g = 0; g < 3; ++g)
        #pragma unroll
        for (int ri = 0; ri < 2; ++ri) {
            const float* wrow = whh + (size_t)d * G3 * HDIM
                + (size_t)(g * 768 + j0 + wave + 4 * ri) * HDIM;
            #pragma unroll
            for (int i = 0; i < 3; ++i)
                w[g * 2 + ri][i] = *(const float4*)(wrow + i * 256 + lane * 4);
        }

    // Gate lanes (wave 0, tid<8): row = j0 + tid; constants + initial h.
    float bh_r = 0.f, bh_z = 0.f, bh_n = 0.f, hprev = 0.f;
    if (tid < 8) {
        const int row = j0 + tid;
        bh_r  = bhh[d * G3 +        row];
        bh_z  = bhh[d * G3 +  768 + row];
        bh_n  = bhh[d * G3 + 1536 + row];
        hprev = h0[d * 768 + row];
    }

    for (int t = 0; t < T_STEPS; ++t) {
        // Gi prefetch for the gate lanes (in flight during the poll).
        float gi_r = 0.f, gi_z = 0.f, gi_n = 0.f;
        if (tid < 8) {
            const float* gip = Gi + ((size_t)t * 2 + d) * G3;
            gi_r = gip[        j0 + tid];
            gi_z = gip[ 768 + j0 + tid];
            gi_n = gip[1536 + j0 + tid];
        }

        // --- Phase 1: poll (waves 0+1), write h into hsh[t&1] ---
        if (tid < 96) {
            float hv[8];
            if (t == 0) {
                const float* src = h0 + d * 768 + tid * 8;
                #pragma unroll
                for (int i = 0; i < 8; ++i) hv[i] = src[i];
            } else {
                const unsigned long long* src = exch
                    + (size_t)((((t - 1) & 1) * 2 + d)) * 768 + tid * 8;
                unsigned long long v[8];
                bool ok;
                do {
                    #pragma unroll
                    for (int i = 0; i < 8; ++i) v[i] = ld_pair(src + i);
                    ok = true;
                    #pragma unroll
                    for (int i = 0; i < 8; ++i)
                        ok &= ((unsigned)v[i] >= (unsigned)t);
                } while (!ok);
                #pragma unroll
                for (int i = 0; i < 8; ++i)
                    hv[i] = __uint_as_float((unsigned)(v[i] >> 32));
            }
            #pragma unroll
            for (int i = 0; i < 8; ++i) hsh[t & 1][tid * 8 + i] = hv[i];
        }
        __syncthreads();

        // --- Phase 2: wave-autonomous dot + butterfly ---
        const float* hb = hsh[t & 1];
        float4 h4[3];
        #pragma unroll
        for (int i = 0; i < 3; ++i)
            h4[i] = *(const float4*)&hb[i * 256 + lane * 4];

        float S[6];
        #pragma unroll
        for (int m = 0; m < 6; ++m) {
            float s = 0.f;
            s = fmaf(w[m][0].x, h4[0].x, s); s = fmaf(w[m][0].y, h4[0].y, s);
            s = fmaf(w[m][0].z, h4[0].z, s); s = fmaf(w[m][0].w, h4[0].w, s);
            s = fmaf(w[m][1].x, h4[1].x, s); s = fmaf(w[m][1].y, h4[1].y, s);
            s = fmaf(w[m][1].z, h4[1].z, s); s = fmaf(w[m][1].w, h4[1].w, s);
            s = fmaf(w[m][2].x, h4[2].x, s); s = fmaf(w[m][2].y, h4[2].y, s);
            s = fmaf(w[m][2].z, h4[2].z, s); s = fmaf(w[m][2].w, h4[2].w, s);
            S[m] = s;
        }
        #pragma unroll
        for (int sft = 1; sft < 64; sft <<= 1) {
            #pragma unroll
            for (int m = 0; m < 6; ++m) S[m] += __shfl_xor(S[m], sft);
        }
        if (lane < 6) gsum[wave * 6 + lane] = S[lane];
        __syncthreads();

        // --- Phase 3: gates + single-transaction publish (wave 0, tid<8) ---
        if (tid < 8) {
            const int wv = tid & 3, ri = tid >> 2;   // row j0+tid = j0+wv+4*ri
            float Sr = gsum[wv * 6 + 0 + ri];
            float Sz = gsum[wv * 6 + 2 + ri];
            float Sn = gsum[wv * 6 + 4 + ri];
            float r = sigf(gi_r + Sr + bh_r);
            float z = sigf(gi_z + Sz + bh_z);
            float n = tanhf(gi_n + r * (Sn + bh_n));
            float hn = (1.0f - z) * n + z * hprev;
            hprev = hn;
            unsigned long long pair =
                ((unsigned long long)__float_as_uint(hn) << 32)
                | (unsigned long long)(unsigned)(t + 1);
            st_pair(exch + (size_t)(((t & 1) * 2 + d)) * 768 + j0 + tid, pair);
            Hout[((size_t)t * 2 + d) * 768 + j0 + tid] = hn;
        }
        // no third sync: next-step gsum writes are ordered behind wave-0's
        // gate reads by the next step's phase-1/2 barrier; hsh is
        // parity-staggered (see header).
    }
}

// ---------------------------------------------------------------------------
// Final FC + sigmoid: out[r] = sigmoid(fc_w[r] . hin + fc_b[r]); one wave/row.
// ---------------------------------------------------------------------------
__device__ __forceinline__ float dot4(float4 a, float4 b) {
    return a.x * b.x + a.y * b.y + a.z * b.z + a.w * b.w;
}

__global__ __launch_bounds__(64)
void fc_sig(const float* __restrict__ hin, const float* __restrict__ fw,
            const float* __restrict__ fb, float* __restrict__ out) {
    const int lane = threadIdx.x;
    const int row  = blockIdx.x;
    const float* wr = fw + (size_t)row * HC;
    float acc = 0.0f;
    #pragma unroll
    for (int i = 0; i < 6; ++i) {
        float4 w4 = *(const float4*)(wr  + i * 256 + lane * 4);
        float4 h4 = *(const float4*)(hin + i * 256 + lane * 4);
        acc += dot4(w4, h4);
    }
    #pragma unroll
    for (int s = 1; s < 64; s <<= 1) acc += __shfl_xor(acc, s);
    if (lane == 0) out[row] = sigf(acc + fb[row]);
}

// ---------------------------------------------------------------------------
extern "C" void kernel_launch(void* const* d_in, const int* in_sizes, int n_in,
                              void* d_out, int out_size, void* d_ws, size_t ws_size,
                              hipStream_t stream) {
    (void)in_sizes; (void)n_in; (void)out_size; (void)ws_size;

    const float* x     = (const float*)d_in[0];   // [8192,512]
    const float* h0    = (const float*)d_in[1];   // [4,768]
    const float* w_ih0 = (const float*)d_in[2];   // [2,2304,512]
    const float* w_hh0 = (const float*)d_in[3];   // [2,2304,768]
    const float* b_ih0 = (const float*)d_in[4];   // [2,2304]
    const float* b_hh0 = (const float*)d_in[5];
    const float* w_ih1 = (const float*)d_in[6];   // [2,2304,1536]
    const float* w_hh1 = (const float*)d_in[7];
    const float* b_ih1 = (const float*)d_in[8];
    const float* b_hh1 = (const float*)d_in[9];
    const float* fc_w  = (const float*)d_in[10];  // [256,1536]
    const float* fc_b  = (const float*)d_in[11];  // [256]
    float* out = (float*)d_out;

    char* ws = (char*)d_ws;
    // Exchange pair buffers (tags must start 0): 2*2*768*8 B = 24 KiB each.
    unsigned long long* exch0 = (unsigned long long*)(ws + 4096);
    unsigned long long* exch1 = (unsigned long long*)(ws + 4096 + 24576);
    float* Gi    = (float*)(ws + 65536);           // [8192][4608] fp32 = 144 MiB
    size_t gi_bytes = (size_t)T_STEPS * NDR * sizeof(float);
    float* Hout  = (float*)(ws + 65536 + gi_bytes); // [8192][2][768] = 48 MiB

    hipMemsetAsync(ws, 0, 65536, stream);

    dim3 ggrid(NDR / 128, T_STEPS / 128);  // (36, 64)

    // Phase 1: Gi0 = x @ w_ih0^T + b_ih0
    gemm_xwt<<<ggrid, 256, 0, stream>>>(x, w_ih0, b_ih0, Gi, T_STEPS, NDR, 512);
    // Phase 2: layer-0 recurrence, store all h0[t]
    gru_rec<<<NWG, 256, 0, stream>>>(Gi, w_hh0, b_hh0, h0, exch0, Hout);
    // Phase 3: Gi1 = concat_h0 @ w_ih1^T + b_ih1
    gemm_xwt<<<ggrid, 256, 0, stream>>>(Hout, w_ih1, b_ih1, Gi, T_STEPS, NDR, HC);
    // Phase 4: layer-1 recurrence
    gru_rec<<<NWG, 256, 0, stream>>>(Gi, w_hh1, b_hh1, h0 + 2 * HDIM, exch1, Hout);
    // Phase 5: y = sigmoid(fc_w @ h_last + fc_b)
    fc_sig<<<256, 64, 0, stream>>>(Hout + (size_t)(T_STEPS - 1) * HC,
                                   fc_w, fc_b, out);
}